// Round 6
// baseline (571.703 us; speedup 1.0000x reference)
//
#include <hip/hip_runtime.h>
#include <hip/hip_bf16.h>

#define B_ 8
#define S_ 1024
#define D_ 512
#define H_ 8
#define DK_ 64
#define HD_ 4096   // H_*D_

typedef __attribute__((ext_vector_type(8))) short bf16x8;
typedef __attribute__((ext_vector_type(4))) float f32x4;

static __device__ __forceinline__ float bf2f(unsigned short u) {
    unsigned v = ((unsigned)u) << 16;
    return __uint_as_float(v);
}
static __device__ __forceinline__ unsigned short f2bf(float f) {
    unsigned u = __float_as_uint(f);
    unsigned r = (u + 0x7fffu + ((u >> 16) & 1u)) >> 16;  // RNE
    return (unsigned short)r;
}

// P_lds index: [ql][k] with 16B-slot XOR swizzle (slot ^= ql&7). Units: shorts.
static __device__ __forceinline__ int plidx(int ql, int k) {
    return ql * 1024 + ((((k >> 3) ^ (ql & 7))) << 3) + (k & 7);
}

// ---------------------------------------------------------------------------
// K1: P = (X @ W^T + bias) * scale, bf16 out at [B][H][S][dk]. grid (128,8).
// ---------------------------------------------------------------------------
__global__ __launch_bounds__(256) void proj_kernel(
    const float* __restrict__ X, const float* __restrict__ W,
    const float* __restrict__ bias, unsigned short* __restrict__ P, float scale)
{
    const int K = D_;
    __shared__ float As[16][68];
    __shared__ float Bs[16][68];
    const int t  = threadIdx.x;
    const int m0 = blockIdx.x * 64;
    const int n0 = blockIdx.y * 64;
    const int lr = t >> 2;
    const int lc = (t & 3) << 2;
    const int ty = t >> 4;
    const int tx = t & 15;
    float acc[4][4] = {};
    for (int k0 = 0; k0 < K; k0 += 16) {
        float4 a4 = *(const float4*)&X[(size_t)(m0 + lr) * K + k0 + lc];
        As[lc + 0][lr] = a4.x; As[lc + 1][lr] = a4.y;
        As[lc + 2][lr] = a4.z; As[lc + 3][lr] = a4.w;
        float4 b4 = *(const float4*)&W[(size_t)(n0 + lr) * K + k0 + lc];
        Bs[lc + 0][lr] = b4.x; Bs[lc + 1][lr] = b4.y;
        Bs[lc + 2][lr] = b4.z; Bs[lc + 3][lr] = b4.w;
        __syncthreads();
        #pragma unroll
        for (int kk = 0; kk < 16; ++kk) {
            float4 av = *(const float4*)&As[kk][ty * 4];
            float4 bv = *(const float4*)&Bs[kk][tx * 4];
            float a[4] = {av.x, av.y, av.z, av.w};
            float b[4] = {bv.x, bv.y, bv.z, bv.w};
            #pragma unroll
            for (int i = 0; i < 4; ++i)
                #pragma unroll
                for (int j = 0; j < 4; ++j) acc[i][j] += a[i] * b[j];
        }
        __syncthreads();
    }
    const int b = m0 >> 10;           // 64-row tile never crosses b
    #pragma unroll
    for (int i = 0; i < 4; ++i) {
        int m = m0 + ty * 4 + i;
        int s = m & 1023;
        #pragma unroll
        for (int j = 0; j < 4; ++j) {
            int n = n0 + tx * 4 + j;
            int h = n >> 6, dk = n & 63;
            P[((((size_t)b * H_ + h) * S_) + s) * DK_ + dk] = f2bf((acc[i][j] + bias[n]) * scale);
        }
    }
}

// ---------------------------------------------------------------------------
// K2: V transpose+convert: Vt[b][e][s] bf16 from V[b][s][e] f32.
// ---------------------------------------------------------------------------
__global__ __launch_bounds__(256) void vt_kernel(
    const float* __restrict__ V, unsigned short* __restrict__ Vt)
{
    __shared__ float tile[32][33];
    const int b = blockIdx.z, s0 = blockIdx.x * 32, e0 = blockIdx.y * 32;
    const int t = threadIdx.x;
    const int r = t >> 3, c4 = (t & 7) * 4;
    float4 v = *(const float4*)&V[((size_t)b * S_ + s0 + r) * D_ + e0 + c4];
    tile[r][c4 + 0] = v.x; tile[r][c4 + 1] = v.y;
    tile[r][c4 + 2] = v.z; tile[r][c4 + 3] = v.w;
    __syncthreads();
    ushort4 u;
    u.x = f2bf(tile[c4 + 0][r]); u.y = f2bf(tile[c4 + 1][r]);
    u.z = f2bf(tile[c4 + 2][r]); u.w = f2bf(tile[c4 + 3][r]);
    *(ushort4*)&Vt[((size_t)b * D_ + e0 + r) * S_ + s0 + c4] = u;
}

// ---------------------------------------------------------------------------
// K3: Wo f32 -> bf16.
// ---------------------------------------------------------------------------
__global__ __launch_bounds__(256) void wobf_kernel(
    const float* __restrict__ Wo, unsigned short* __restrict__ Wobf)
{
    const size_t i = ((size_t)blockIdx.x * 256 + threadIdx.x) * 4;
    float4 v = *(const float4*)&Wo[i];
    ushort4 u = { f2bf(v.x), f2bf(v.y), f2bf(v.z), f2bf(v.w) };
    *(ushort4*)&Wobf[i] = u;
}

// ---------------------------------------------------------------------------
// K4: FUSED attention, 16 waves (1024 thr). Swapped QK^T (per-wave k-window
// 64) -> reg softmax -> P bf16 -> swizzled LDS -> coalesced attn f32 write
// from LDS -> PV MFMA -> AV bf16. grid (16, 64).
// ---------------------------------------------------------------------------
__global__ __launch_bounds__(1024, 4) void fused_attn(
    const unsigned short* __restrict__ Qbf,   // [B][H][S][64], pre-scaled 0.125
    const unsigned short* __restrict__ Kbf,   // [B][H][S][64]
    const unsigned short* __restrict__ Vt,    // [B][512][1024]
    float* __restrict__ attn,                 // [B][H][S][S]
    unsigned short* __restrict__ AV)          // [B*S][4096]
{
    const int bh = blockIdx.y;
    const int b = bh >> 3, h = bh & 7;
    const int q0 = blockIdx.x * 64;
    const unsigned short* Qb = Qbf + (size_t)bh * S_ * DK_;
    const unsigned short* Kb = Kbf + (size_t)bh * S_ * DK_;
    const unsigned short* Vb = Vt + (size_t)b * D_ * S_;
    float* outp = attn + ((size_t)bh << 20);

    __shared__ unsigned short PL[64 * 1024];   // 128 KB, swizzled [q][k] bf16
    __shared__ float redm[64][16];
    __shared__ float rowm[64];

    const int t = threadIdx.x;
    const int wave = t >> 6, lane = t & 63;
    const int wcol = wave * 64;     // QK: this wave's k-col window
    const int lr = lane & 15;
    const int g  = lane >> 4;       // 0..3

    // ---- QK^T (swapped): acc[r][c][i] = S[k = wcol+r*16+g*4+i][q = c*16+lr]
    f32x4 acc[4][4];
    #pragma unroll
    for (int r = 0; r < 4; ++r)
        #pragma unroll
        for (int c = 0; c < 4; ++c) acc[r][c] = (f32x4){0.f, 0.f, 0.f, 0.f};

    #pragma unroll
    for (int kk = 0; kk < 2; ++kk) {
        bf16x8 af[4];   // K fragments (A operand, rows = k-cols)
        #pragma unroll
        for (int r = 0; r < 4; ++r)
            af[r] = *(const bf16x8*)&Kb[(size_t)(wcol + r * 16 + lr) * DK_ + kk * 32 + g * 8];
        bf16x8 qf[4];   // Q fragments (B operand, cols = q-rows)
        #pragma unroll
        for (int c = 0; c < 4; ++c)
            qf[c] = *(const bf16x8*)&Qb[(size_t)(q0 + c * 16 + lr) * DK_ + kk * 32 + g * 8];
        #pragma unroll
        for (int r = 0; r < 4; ++r)
            #pragma unroll
            for (int c = 0; c < 4; ++c)
                acc[r][c] = __builtin_amdgcn_mfma_f32_16x16x32_bf16(af[r], qf[c], acc[r][c], 0, 0, 0);
    }

    // ---- softmax stage 1: wave-local max over this wave's 64-k window
    float mloc[4];
    #pragma unroll
    for (int c = 0; c < 4; ++c) {
        float m = acc[0][c][0];
        #pragma unroll
        for (int r = 0; r < 4; ++r)
            #pragma unroll
            for (int i = 0; i < 4; ++i) m = fmaxf(m, acc[r][c][i]);
        m = fmaxf(m, __shfl_xor(m, 16));
        m = fmaxf(m, __shfl_xor(m, 32));
        mloc[c] = m;
    }
    if (lane < 16) {
        #pragma unroll
        for (int c = 0; c < 4; ++c) redm[c * 16 + lane][wave] = mloc[c];
    }
    __syncthreads();
    if (t < 64) {
        float m = redm[t][0];
        #pragma unroll
        for (int w = 1; w < 16; ++w) m = fmaxf(m, redm[t][w]);
        rowm[t] = m;
    }
    __syncthreads();
    // ---- exp + wave-local sum
    float sloc[4];
    #pragma unroll
    for (int c = 0; c < 4; ++c) {
        const float m = rowm[c * 16 + lr];
        float s = 0.f;
        #pragma unroll
        for (int r = 0; r < 4; ++r)
            #pragma unroll
            for (int i = 0; i < 4; ++i) {
                float p = __expf(acc[r][c][i] - m);
                acc[r][c][i] = p;
                s += p;
            }
        s += __shfl_xor(s, 16);
        s += __shfl_xor(s, 32);
        sloc[c] = s;
    }
    if (lane < 16) {
        #pragma unroll
        for (int c = 0; c < 4; ++c) redm[c * 16 + lane][wave] = sloc[c];
    }
    __syncthreads();
    if (t < 64) {
        float s = redm[t][0];
        #pragma unroll
        for (int w = 1; w < 16; ++w) s += redm[t][w];
        rowm[t] = 1.0f / s;
    }
    __syncthreads();

    // ---- normalize; pack P bf16 -> swizzled LDS
    #pragma unroll
    for (int c = 0; c < 4; ++c) {
        const int ql = c * 16 + lr;
        const float ri = rowm[ql];
        #pragma unroll
        for (int r = 0; r < 4; ++r) {
            f32x4 v = acc[r][c];
            v[0] *= ri; v[1] *= ri; v[2] *= ri; v[3] *= ri;
            const int k = wcol + r * 16 + g * 4;
            unsigned p01 = (unsigned)f2bf(v[0]) | ((unsigned)f2bf(v[1]) << 16);
            unsigned p23 = (unsigned)f2bf(v[2]) | ((unsigned)f2bf(v[3]) << 16);
            uint2 pk = { p01, p23 };
            *(uint2*)&PL[plidx(ql, k)] = pk;
        }
    }
    __syncthreads();

    // ---- coalesced attn f32 write from PL (bf16 -> f32 unpack)
    {
        const int arow = t >> 4;          // 0..63
        const int akb  = (t & 15) * 8;    // 0..120
        float* rowp = outp + ((size_t)(q0 + arow) << 10);
        #pragma unroll
        for (int j = 0; j < 8; ++j) {
            const int k = akb + j * 128;
            uint4 u = *(const uint4*)&PL[plidx(arow, k)];
            float4 f0, f1;
            f0.x = __uint_as_float((u.x & 0xffffu) << 16);
            f0.y = __uint_as_float(u.x & 0xffff0000u);
            f0.z = __uint_as_float((u.y & 0xffffu) << 16);
            f0.w = __uint_as_float(u.y & 0xffff0000u);
            f1.x = __uint_as_float((u.z & 0xffffu) << 16);
            f1.y = __uint_as_float(u.z & 0xffff0000u);
            f1.z = __uint_as_float((u.w & 0xffffu) << 16);
            f1.w = __uint_as_float(u.w & 0xffff0000u);
            *(float4*)&rowp[k] = f0;
            *(float4*)&rowp[k + 4] = f1;
        }
    }

    // ---- PV: O[q][e]; wave owns e in [wave*32, +32)
    const int we = wave * 32;
    f32x4 accv[4][2];
    #pragma unroll
    for (int r = 0; r < 4; ++r)
        #pragma unroll
        for (int c = 0; c < 2; ++c) accv[r][c] = (f32x4){0.f, 0.f, 0.f, 0.f};

    for (int k0 = 0; k0 < S_; k0 += 32) {
        bf16x8 pa[4];
        #pragma unroll
        for (int r = 0; r < 4; ++r)
            pa[r] = *(const bf16x8*)&PL[plidx(r * 16 + lr, k0 + g * 8)];
        #pragma unroll
        for (int c = 0; c < 2; ++c) {
            const int e = we + c * 16 + lr;
            bf16x8 vf = *(const bf16x8*)&Vb[(size_t)e * S_ + k0 + g * 8];
            #pragma unroll
            for (int r = 0; r < 4; ++r)
                accv[r][c] = __builtin_amdgcn_mfma_f32_16x16x32_bf16(pa[r], vf, accv[r][c], 0, 0, 0);
        }
    }
    #pragma unroll
    for (int r = 0; r < 4; ++r) {
        #pragma unroll
        for (int c = 0; c < 2; ++c) {
            const int e = we + c * 16 + lr;
            #pragma unroll
            for (int i = 0; i < 4; ++i) {
                const int row = q0 + r * 16 + g * 4 + i;
                AV[((size_t)(b * S_ + row)) * HD_ + h * D_ + e] = f2bf(accv[r][c][i]);
            }
        }
    }
}

// ---------------------------------------------------------------------------
// K5: Y = AV(bf16)[8192x4096] @ Wobf^T[512x4096] + bo + value.
// Tile 32 x 512 (full N). 16 waves; wave owns n-cols [wave*32,+32).
// grid 256 (1/CU, 16 waves/CU). AV read exactly once; Wobf L2-resident.
// ---------------------------------------------------------------------------
__global__ __launch_bounds__(1024, 4) void out_mfma2(
    const unsigned short* __restrict__ AV, const unsigned short* __restrict__ Wobf,
    const float* __restrict__ bo, const float* __restrict__ Vres,
    float* __restrict__ Y)
{
    const int m0 = blockIdx.x * 32;
    const int t = threadIdx.x;
    const int wave = t >> 6, lane = t & 63;
    const int wc = wave * 32;
    const int lr = lane & 15;
    const int g  = lane >> 4;

    f32x4 acc[2][2];
    #pragma unroll
    for (int r = 0; r < 2; ++r)
        #pragma unroll
        for (int c = 0; c < 2; ++c) acc[r][c] = (f32x4){0.f, 0.f, 0.f, 0.f};

    for (int k0 = 0; k0 < HD_; k0 += 32) {
        bf16x8 af[2];
        #pragma unroll
        for (int r = 0; r < 2; ++r)
            af[r] = *(const bf16x8*)&AV[(size_t)(m0 + r * 16 + lr) * HD_ + k0 + g * 8];
        #pragma unroll
        for (int c = 0; c < 2; ++c) {
            bf16x8 bf = *(const bf16x8*)&Wobf[(size_t)(wc + c * 16 + lr) * HD_ + k0 + g * 8];
            #pragma unroll
            for (int r = 0; r < 2; ++r)
                acc[r][c] = __builtin_amdgcn_mfma_f32_16x16x32_bf16(af[r], bf, acc[r][c], 0, 0, 0);
        }
    }
    #pragma unroll
    for (int r = 0; r < 2; ++r) {
        #pragma unroll
        for (int c = 0; c < 2; ++c) {
            const int n = wc + c * 16 + lr;
            #pragma unroll
            for (int i = 0; i < 4; ++i) {
                const int m = m0 + r * 16 + g * 4 + i;
                const size_t o = (size_t)m * D_ + n;
                Y[o] = acc[r][c][i] + bo[n] + Vres[o];
            }
        }
    }
}

// ---------------------------------------------------------------------------
// K6: LayerNorm in place. grid 2048, block 256.
// ---------------------------------------------------------------------------
__global__ __launch_bounds__(256) void ln_kernel(
    float* __restrict__ Y, const float* __restrict__ gamma,
    const float* __restrict__ beta)
{
    const int lane = threadIdx.x & 63;
    const int wave = threadIdx.x >> 6;
    const size_t row = (size_t)blockIdx.x * 4 + wave;
    float* p = Y + row * D_;
    float4 v0 = *(float4*)&p[lane * 4];
    float4 v1 = *(float4*)&p[256 + lane * 4];
    float s = v0.x + v0.y + v0.z + v0.w + v1.x + v1.y + v1.z + v1.w;
    float q = v0.x * v0.x + v0.y * v0.y + v0.z * v0.z + v0.w * v0.w +
              v1.x * v1.x + v1.y * v1.y + v1.z * v1.z + v1.w * v1.w;
    #pragma unroll
    for (int m = 1; m < 64; m <<= 1) {
        s += __shfl_xor(s, m);
        q += __shfl_xor(q, m);
    }
    const float mu  = s * (1.f / 512.f);
    const float var = q * (1.f / 512.f) - mu * mu;
    const float r = rsqrtf(var + 1e-5f);
    const float4 g0 = *(const float4*)&gamma[lane * 4];
    const float4 g1 = *(const float4*)&gamma[256 + lane * 4];
    const float4 b0 = *(const float4*)&beta[lane * 4];
    const float4 b1 = *(const float4*)&beta[256 + lane * 4];
    v0.x = (v0.x - mu) * r * g0.x + b0.x;
    v0.y = (v0.y - mu) * r * g0.y + b0.y;
    v0.z = (v0.z - mu) * r * g0.z + b0.z;
    v0.w = (v0.w - mu) * r * g0.w + b0.w;
    v1.x = (v1.x - mu) * r * g1.x + b1.x;
    v1.y = (v1.y - mu) * r * g1.y + b1.y;
    v1.z = (v1.z - mu) * r * g1.z + b1.z;
    v1.w = (v1.w - mu) * r * g1.w + b1.w;
    *(float4*)&p[lane * 4] = v0;
    *(float4*)&p[256 + lane * 4] = v1;
}

// ---------------------------------------------------------------------------
extern "C" void kernel_launch(void* const* d_in, const int* in_sizes, int n_in,
                              void* d_out, int out_size, void* d_ws, size_t ws_size,
                              hipStream_t stream)
{
    const float* query = (const float*)d_in[0];
    const float* key   = (const float*)d_in[1];
    const float* value = (const float*)d_in[2];
    const float* Wq    = (const float*)d_in[3];
    const float* bq    = (const float*)d_in[4];
    const float* Wk    = (const float*)d_in[5];
    const float* bk    = (const float*)d_in[6];
    const float* Wo    = (const float*)d_in[7];
    const float* bo    = (const float*)d_in[8];
    const float* gamma = (const float*)d_in[9];
    const float* beta  = (const float*)d_in[10];

    float* out  = (float*)d_out;                       // [B,S,D] (16 MiB)
    float* attn = out + (size_t)B_ * S_ * D_;          // [B,H,S,S] (256 MiB)

    char* ws = (char*)d_ws;
    // ws (76 MB): AV [0,64) bf16 ; Vt [64,72) bf16 ; Wobf [72,76) bf16.
    unsigned short* AV   = (unsigned short*)ws;
    unsigned short* Vt   = (unsigned short*)(ws + ((size_t)64 << 20));
    unsigned short* Wobf = (unsigned short*)(ws + ((size_t)72 << 20));
    // Qbf/Kbf (8 MiB each = exactly the 16 MiB OUT region of d_out);
    // dead before out_mfma2 overwrites that region (stream-ordered).
    // Offsets in SHORTS: Kbf at 4M shorts = byte offset 8 MiB.
    unsigned short* Qbf  = (unsigned short*)d_out;
    unsigned short* Kbf  = (unsigned short*)d_out + ((size_t)4 << 20);

    vt_kernel<<<dim3(32, 16, 8), 256, 0, stream>>>(value, Vt);
    wobf_kernel<<<dim3(2048), 256, 0, stream>>>(Wo, Wobf);
    proj_kernel<<<dim3(128, 8), 256, 0, stream>>>(query, Wq, bq, Qbf, 0.125f);
    proj_kernel<<<dim3(128, 8), 256, 0, stream>>>(key,   Wk, bk, Kbf, 1.0f);
    fused_attn<<<dim3(16, 64), 1024, 0, stream>>>(Qbf, Kbf, Vt, attn, AV);
    out_mfma2<<<dim3(256), 1024, 0, stream>>>(AV, Wobf, bo, value, out);
    ln_kernel<<<dim3(2048), 256, 0, stream>>>(out, gamma, beta);
}

// Round 7
// 396.619 us; speedup vs baseline: 1.4414x; 1.4414x over previous
//
#include <hip/hip_runtime.h>
#include <hip/hip_bf16.h>

#define B_ 8
#define S_ 1024
#define D_ 512
#define H_ 8
#define DK_ 64
#define HD_ 4096   // H_*D_

typedef __attribute__((ext_vector_type(8))) short bf16x8;
typedef __attribute__((ext_vector_type(4))) float f32x4;

static __device__ __forceinline__ unsigned short f2bf(float f) {
    unsigned u = __float_as_uint(f);
    unsigned r = (u + 0x7fffu + ((u >> 16) & 1u)) >> 16;  // RNE
    return (unsigned short)r;
}

// async global(16B/lane) -> LDS (wave-uniform base + lane*16)
static __device__ __forceinline__ void gload16(const unsigned short* g, unsigned short* l) {
    __builtin_amdgcn_global_load_lds(
        (const __attribute__((address_space(1))) void*)g,
        (__attribute__((address_space(3))) void*)l, 16, 0, 0);
}

// P_lds index: [ql][k] with 16B-slot XOR swizzle (slot ^= ql&7). Units: shorts.
static __device__ __forceinline__ int plidx(int ql, int k) {
    return ql * 1024 + ((((k >> 3) ^ (ql & 7))) << 3) + (k & 7);
}

// ---------------------------------------------------------------------------
// K0: generic f32 -> bf16 convert, 4 elems/thread. grid = count/1024.
// ---------------------------------------------------------------------------
__global__ __launch_bounds__(256) void cvt_kernel(
    const float* __restrict__ src, unsigned short* __restrict__ dst)
{
    const size_t i = ((size_t)blockIdx.x * 256 + threadIdx.x) * 4;
    float4 v = *(const float4*)&src[i];
    ushort4 u = { f2bf(v.x), f2bf(v.y), f2bf(v.z), f2bf(v.w) };
    *(ushort4*)&dst[i] = u;
}

// ---------------------------------------------------------------------------
// K1: V transpose+convert: Vt[b][e][s] bf16 from V[b][s][e] f32.
// ---------------------------------------------------------------------------
__global__ __launch_bounds__(256) void vt_kernel(
    const float* __restrict__ V, unsigned short* __restrict__ Vt)
{
    __shared__ float tile[32][33];
    const int b = blockIdx.z, s0 = blockIdx.x * 32, e0 = blockIdx.y * 32;
    const int t = threadIdx.x;
    const int r = t >> 3, c4 = (t & 7) * 4;
    float4 v = *(const float4*)&V[((size_t)b * S_ + s0 + r) * D_ + e0 + c4];
    tile[r][c4 + 0] = v.x; tile[r][c4 + 1] = v.y;
    tile[r][c4 + 2] = v.z; tile[r][c4 + 3] = v.w;
    __syncthreads();
    ushort4 u;
    u.x = f2bf(tile[c4 + 0][r]); u.y = f2bf(tile[c4 + 1][r]);
    u.z = f2bf(tile[c4 + 2][r]); u.w = f2bf(tile[c4 + 3][r]);
    *(ushort4*)&Vt[((size_t)b * D_ + e0 + r) * S_ + s0 + c4] = u;
}

// ---------------------------------------------------------------------------
// K2: 128x128-tile bf16 MFMA GEMM, BK=32, double-buffered LDS staged via
// global_load_lds (16B), source-side XOR slot swizzle (4-way reads).
// C = A[M x K] @ Bw[512 x K]^T. 256 thr (4 waves, 2x2), 4x4 frags/wave.
// grid 256, XCD-chunked swizzle so the 4 n-blocks of one m share an L2.
// MODE 0: P[b][h][s][dk] = bf16((C + bias) * scale)   (QK projection)
// MODE 1: Y = C + bias + Vres (f32)                   (output projection)
// ---------------------------------------------------------------------------
template<int KDIM, int MODE>
__global__ __launch_bounds__(256) void gemm128(
    const unsigned short* __restrict__ A, const unsigned short* __restrict__ Bw,
    const float* __restrict__ bias, const float* __restrict__ Vres,
    void* __restrict__ Out, float scale)
{
    const int o = blockIdx.x;
    const int nb = (o & 7) * 32 + (o >> 3);    // XCD-chunked bijection (256=8*32)
    const int m0 = (nb >> 2) * 128;
    const int n0 = (nb & 3) * 128;

    __shared__ __align__(16) unsigned short As[2][128 * 32];
    __shared__ __align__(16) unsigned short Bs[2][128 * 32];

    const int t = threadIdx.x;
    const int wave = t >> 6, lane = t & 63;
    const int wr = wave >> 1, wc = wave & 1;
    const int lr = lane & 15, g = lane >> 4;
    const int gx = (g ^ (lr & 3)) << 3;        // swizzled k-slot (shorts)

    f32x4 acc[4][4];
    #pragma unroll
    for (int r = 0; r < 4; ++r)
        #pragma unroll
        for (int c = 0; c < 4; ++c) acc[r][c] = (f32x4){0.f, 0.f, 0.f, 0.f};

    const int sub = lane >> 2;                              // row within chunk
    const int cb  = (((lane & 3) ^ (sub & 3)) << 3);        // swizzled src col

    auto stage = [&](int buf, int k0) {
        #pragma unroll
        for (int s = 0; s < 2; ++s) {
            const int chunk = s * 4 + wave;
            const int row = chunk * 16 + sub;
            gload16(&A [(size_t)(m0 + row) * KDIM + k0 + cb], &As[buf][chunk * 512]);
            gload16(&Bw[(size_t)(n0 + row) * KDIM + k0 + cb], &Bs[buf][chunk * 512]);
        }
    };
    auto compute = [&](int cur) {
        bf16x8 af[4], bfr[4];
        #pragma unroll
        for (int r = 0; r < 4; ++r)
            af[r] = *(const bf16x8*)&As[cur][(wr * 64 + r * 16 + lr) * 32 + gx];
        #pragma unroll
        for (int c = 0; c < 4; ++c)
            bfr[c] = *(const bf16x8*)&Bs[cur][(wc * 64 + c * 16 + lr) * 32 + gx];
        #pragma unroll
        for (int c = 0; c < 4; ++c)
            #pragma unroll
            for (int r = 0; r < 4; ++r)
                acc[r][c] = __builtin_amdgcn_mfma_f32_16x16x32_bf16(af[r], bfr[c], acc[r][c], 0, 0, 0);
    };

    const int NT = KDIM / 32;
    stage(0, 0);
    __syncthreads();
    int cur = 0;
    for (int tt = 0; tt < NT - 1; ++tt) {
        stage(cur ^ 1, (tt + 1) * 32);   // issue next-tile loads first
        compute(cur);                    // MFMA hides the load latency
        __syncthreads();                 // vmcnt(0) drain + WAR protect
        cur ^= 1;
    }
    compute(cur);

    float bn[4];
    #pragma unroll
    for (int c = 0; c < 4; ++c) bn[c] = bias[n0 + wc * 64 + c * 16 + lr];

    #pragma unroll
    for (int r = 0; r < 4; ++r) {
        #pragma unroll
        for (int c = 0; c < 4; ++c) {
            const int n = n0 + wc * 64 + c * 16 + lr;
            #pragma unroll
            for (int i = 0; i < 4; ++i) {
                const int m = m0 + wr * 64 + r * 16 + g * 4 + i;
                if constexpr (MODE == 0) {
                    const int srow = m & 1023, bb = m >> 10;
                    const int h = n >> 6, dk = n & 63;
                    ((unsigned short*)Out)[(((size_t)(bb * H_ + h)) * S_ + srow) * DK_ + dk] =
                        f2bf((acc[r][c][i] + bn[c]) * scale);
                } else {
                    const size_t oo = (size_t)m * D_ + n;
                    ((float*)Out)[oo] = acc[r][c][i] + bn[c] + Vres[oo];
                }
            }
        }
    }
}

// ---------------------------------------------------------------------------
// K3: FUSED attention, 16 waves (1024 thr). Swapped QK^T (per-wave k-window
// 64) -> reg softmax -> P bf16 -> swizzled LDS -> PV MFMA -> attn f32 write
// -> LDS-staged coalesced AV store. grid (16, 64).
// ---------------------------------------------------------------------------
__global__ __launch_bounds__(1024, 4) void fused_attn(
    const unsigned short* __restrict__ Qbf,   // [B][H][S][64], pre-scaled 0.125
    const unsigned short* __restrict__ Kbf,   // [B][H][S][64]
    const unsigned short* __restrict__ Vt,    // [B][512][1024]
    float* __restrict__ attn,                 // [B][H][S][S]
    unsigned short* __restrict__ AV)          // [B*S][4096]
{
    const int bh = blockIdx.y;
    const int b = bh >> 3, h = bh & 7;
    const int q0 = blockIdx.x * 64;
    const unsigned short* Qb = Qbf + (size_t)bh * S_ * DK_;
    const unsigned short* Kb = Kbf + (size_t)bh * S_ * DK_;
    const unsigned short* Vb = Vt + (size_t)b * D_ * S_;
    float* outp = attn + ((size_t)bh << 20);

    __shared__ unsigned short PL[64 * 1024];   // 128 KB, swizzled [q][k] bf16
    __shared__ float redm[64][16];
    __shared__ float rowm[64];

    const int t = threadIdx.x;
    const int wave = t >> 6, lane = t & 63;
    const int wcol = wave * 64;     // QK: this wave's k-col window
    const int lr = lane & 15;
    const int g  = lane >> 4;       // 0..3

    // ---- QK^T (swapped): acc[r][c][i] = S[k = wcol+r*16+g*4+i][q = c*16+lr]
    f32x4 acc[4][4];
    #pragma unroll
    for (int r = 0; r < 4; ++r)
        #pragma unroll
        for (int c = 0; c < 4; ++c) acc[r][c] = (f32x4){0.f, 0.f, 0.f, 0.f};

    #pragma unroll
    for (int kk = 0; kk < 2; ++kk) {
        bf16x8 af[4];   // K fragments (A operand, rows = k-cols)
        #pragma unroll
        for (int r = 0; r < 4; ++r)
            af[r] = *(const bf16x8*)&Kb[(size_t)(wcol + r * 16 + lr) * DK_ + kk * 32 + g * 8];
        bf16x8 qf[4];   // Q fragments (B operand, cols = q-rows)
        #pragma unroll
        for (int c = 0; c < 4; ++c)
            qf[c] = *(const bf16x8*)&Qb[(size_t)(q0 + c * 16 + lr) * DK_ + kk * 32 + g * 8];
        #pragma unroll
        for (int r = 0; r < 4; ++r)
            #pragma unroll
            for (int c = 0; c < 4; ++c)
                acc[r][c] = __builtin_amdgcn_mfma_f32_16x16x32_bf16(af[r], qf[c], acc[r][c], 0, 0, 0);
    }

    // ---- softmax stage 1: wave-local max over this wave's 64-k window
    float mloc[4];
    #pragma unroll
    for (int c = 0; c < 4; ++c) {
        float m = acc[0][c][0];
        #pragma unroll
        for (int r = 0; r < 4; ++r)
            #pragma unroll
            for (int i = 0; i < 4; ++i) m = fmaxf(m, acc[r][c][i]);
        m = fmaxf(m, __shfl_xor(m, 16));
        m = fmaxf(m, __shfl_xor(m, 32));
        mloc[c] = m;
    }
    if (lane < 16) {
        #pragma unroll
        for (int c = 0; c < 4; ++c) redm[c * 16 + lane][wave] = mloc[c];
    }
    __syncthreads();
    if (t < 64) {
        float m = redm[t][0];
        #pragma unroll
        for (int w = 1; w < 16; ++w) m = fmaxf(m, redm[t][w]);
        rowm[t] = m;
    }
    __syncthreads();
    // ---- exp + wave-local sum
    float sloc[4];
    #pragma unroll
    for (int c = 0; c < 4; ++c) {
        const float m = rowm[c * 16 + lr];
        float s = 0.f;
        #pragma unroll
        for (int r = 0; r < 4; ++r)
            #pragma unroll
            for (int i = 0; i < 4; ++i) {
                float p = __expf(acc[r][c][i] - m);
                acc[r][c][i] = p;
                s += p;
            }
        s += __shfl_xor(s, 16);
        s += __shfl_xor(s, 32);
        sloc[c] = s;
    }
    if (lane < 16) {
        #pragma unroll
        for (int c = 0; c < 4; ++c) redm[c * 16 + lane][wave] = sloc[c];
    }
    __syncthreads();
    if (t < 64) {
        float s = redm[t][0];
        #pragma unroll
        for (int w = 1; w < 16; ++w) s += redm[t][w];
        rowm[t] = 1.0f / s;
    }
    __syncthreads();

    // ---- normalize; pack P bf16 -> swizzled LDS
    #pragma unroll
    for (int c = 0; c < 4; ++c) {
        const int ql = c * 16 + lr;
        const float ri = rowm[ql];
        #pragma unroll
        for (int r = 0; r < 4; ++r) {
            f32x4 v = acc[r][c];
            v[0] *= ri; v[1] *= ri; v[2] *= ri; v[3] *= ri;
            const int k = wcol + r * 16 + g * 4;
            unsigned p01 = (unsigned)f2bf(v[0]) | ((unsigned)f2bf(v[1]) << 16);
            unsigned p23 = (unsigned)f2bf(v[2]) | ((unsigned)f2bf(v[3]) << 16);
            uint2 pk = { p01, p23 };
            *(uint2*)&PL[plidx(ql, k)] = pk;
        }
    }
    __syncthreads();

    // ---- PV: O[q][e]; wave owns e in [wave*32, +32)
    const int we = wave * 32;
    f32x4 accv[4][2];
    #pragma unroll
    for (int r = 0; r < 4; ++r)
        #pragma unroll
        for (int c = 0; c < 2; ++c) accv[r][c] = (f32x4){0.f, 0.f, 0.f, 0.f};

    for (int k0 = 0; k0 < S_; k0 += 32) {
        bf16x8 pa[4];
        #pragma unroll
        for (int r = 0; r < 4; ++r)
            pa[r] = *(const bf16x8*)&PL[plidx(r * 16 + lr, k0 + g * 8)];
        #pragma unroll
        for (int c = 0; c < 2; ++c) {
            const int e = we + c * 16 + lr;
            bf16x8 vf = *(const bf16x8*)&Vb[(size_t)e * S_ + k0 + g * 8];
            #pragma unroll
            for (int r = 0; r < 4; ++r)
                accv[r][c] = __builtin_amdgcn_mfma_f32_16x16x32_bf16(pa[r], vf, accv[r][c], 0, 0, 0);
        }
    }

    // ---- coalesced attn f32 write from PL (bf16 -> f32 unpack)
    {
        const int arow = t >> 4;          // 0..63
        const int akb  = (t & 15) * 8;    // 0..120
        float* rowp = outp + ((size_t)(q0 + arow) << 10);
        #pragma unroll
        for (int j = 0; j < 8; ++j) {
            const int k = akb + j * 128;
            uint4 u = *(const uint4*)&PL[plidx(arow, k)];
            float4 f0, f1;
            f0.x = __uint_as_float((u.x & 0xffffu) << 16);
            f0.y = __uint_as_float(u.x & 0xffff0000u);
            f0.z = __uint_as_float((u.y & 0xffffu) << 16);
            f0.w = __uint_as_float(u.y & 0xffff0000u);
            f1.x = __uint_as_float((u.z & 0xffffu) << 16);
            f1.y = __uint_as_float(u.z & 0xffff0000u);
            f1.z = __uint_as_float((u.w & 0xffffu) << 16);
            f1.w = __uint_as_float(u.w & 0xffff0000u);
            *(float4*)&rowp[k] = f0;
            *(float4*)&rowp[k + 4] = f1;
        }
    }
    __syncthreads();   // all PL reads done; PL reusable

    // ---- AV tile -> LDS (XOR swizzled, 4-way-safe), then coalesced store
    unsigned short* PLs = PL;              // [64][512] shorts, swizzled
    #pragma unroll
    for (int r = 0; r < 4; ++r)
        #pragma unroll
        for (int c = 0; c < 2; ++c) {
            const int e = we + c * 16 + lr;
            #pragma unroll
            for (int i = 0; i < 4; ++i) {
                const int q = r * 16 + g * 4 + i;
                PLs[q * 512 + (e ^ ((q & 7) << 3))] = f2bf(accv[r][c][i]);
            }
        }
    __syncthreads();
    {
        const int row = t >> 4;
        unsigned short* avp = AV + ((size_t)(b * S_ + q0 + row)) * HD_ + h * D_;
        #pragma unroll
        for (int j = 0; j < 4; ++j) {
            const int e0 = (t & 15) * 8 + j * 128;
            uint4 u = *(const uint4*)&PLs[row * 512 + (e0 ^ ((row & 7) << 3))];
            *(uint4*)&avp[e0] = u;
        }
    }
}

// ---------------------------------------------------------------------------
// K4: LayerNorm in place. grid 2048, block 256.
// ---------------------------------------------------------------------------
__global__ __launch_bounds__(256) void ln_kernel(
    float* __restrict__ Y, const float* __restrict__ gamma,
    const float* __restrict__ beta)
{
    const int lane = threadIdx.x & 63;
    const int wave = threadIdx.x >> 6;
    const size_t row = (size_t)blockIdx.x * 4 + wave;
    float* p = Y + row * D_;
    float4 v0 = *(float4*)&p[lane * 4];
    float4 v1 = *(float4*)&p[256 + lane * 4];
    float s = v0.x + v0.y + v0.z + v0.w + v1.x + v1.y + v1.z + v1.w;
    float q = v0.x * v0.x + v0.y * v0.y + v0.z * v0.z + v0.w * v0.w +
              v1.x * v1.x + v1.y * v1.y + v1.z * v1.z + v1.w * v1.w;
    #pragma unroll
    for (int m = 1; m < 64; m <<= 1) {
        s += __shfl_xor(s, m);
        q += __shfl_xor(q, m);
    }
    const float mu  = s * (1.f / 512.f);
    const float var = q * (1.f / 512.f) - mu * mu;
    const float r = rsqrtf(var + 1e-5f);
    const float4 g0 = *(const float4*)&gamma[lane * 4];
    const float4 g1 = *(const float4*)&gamma[256 + lane * 4];
    const float4 b0 = *(const float4*)&beta[lane * 4];
    const float4 b1 = *(const float4*)&beta[256 + lane * 4];
    v0.x = (v0.x - mu) * r * g0.x + b0.x;
    v0.y = (v0.y - mu) * r * g0.y + b0.y;
    v0.z = (v0.z - mu) * r * g0.z + b0.z;
    v0.w = (v0.w - mu) * r * g0.w + b0.w;
    v1.x = (v1.x - mu) * r * g1.x + b1.x;
    v1.y = (v1.y - mu) * r * g1.y + b1.y;
    v1.z = (v1.z - mu) * r * g1.z + b1.z;
    v1.w = (v1.w - mu) * r * g1.w + b1.w;
    *(float4*)&p[lane * 4] = v0;
    *(float4*)&p[256 + lane * 4] = v1;
}

// ---------------------------------------------------------------------------
extern "C" void kernel_launch(void* const* d_in, const int* in_sizes, int n_in,
                              void* d_out, int out_size, void* d_ws, size_t ws_size,
                              hipStream_t stream)
{
    const float* query = (const float*)d_in[0];
    const float* key   = (const float*)d_in[1];
    const float* value = (const float*)d_in[2];
    const float* Wq    = (const float*)d_in[3];
    const float* bq    = (const float*)d_in[4];
    const float* Wk    = (const float*)d_in[5];
    const float* bk    = (const float*)d_in[6];
    const float* Wo    = (const float*)d_in[7];
    const float* bo    = (const float*)d_in[8];
    const float* gamma = (const float*)d_in[9];
    const float* beta  = (const float*)d_in[10];

    float* out  = (float*)d_out;                       // [B,S,D] (16 MiB)
    float* attn = out + (size_t)B_ * S_ * D_;          // [B,H,S,S] (256 MiB)
    char*  attnB = (char*)attn;

    char* ws = (char*)d_ws;
    // ws (76 MB): AV [0,64) bf16 ; Vt [64,72) bf16 ; Wobf [72,76) bf16.
    unsigned short* AV   = (unsigned short*)ws;
    unsigned short* Vt   = (unsigned short*)(ws + ((size_t)64 << 20));
    unsigned short* Wobf = (unsigned short*)(ws + ((size_t)72 << 20));
    // Qbf/Kbf (8 MiB each) in the OUT region of d_out (dead before out-GEMM).
    unsigned short* Qbf  = (unsigned short*)d_out;
    unsigned short* Kbf  = (unsigned short*)d_out + ((size_t)4 << 20);  // shorts
    // bf16 copies of X and W live in the tail of the ATTN region — consumed
    // by the projections, which complete before fused_attn overwrites attn.
    unsigned short* Xq   = (unsigned short*)(attnB + ((size_t)200 << 20));
    unsigned short* Xk   = (unsigned short*)(attnB + ((size_t)210 << 20));
    unsigned short* Wqbf = (unsigned short*)(attnB + ((size_t)220 << 20));
    unsigned short* Wkbf = (unsigned short*)(attnB + ((size_t)221 << 20));

    cvt_kernel<<<4096, 256, 0, stream>>>(query, Xq);
    cvt_kernel<<<4096, 256, 0, stream>>>(key,   Xk);
    cvt_kernel<<<256,  256, 0, stream>>>(Wq, Wqbf);
    cvt_kernel<<<256,  256, 0, stream>>>(Wk, Wkbf);
    cvt_kernel<<<2048, 256, 0, stream>>>(Wo, Wobf);
    vt_kernel<<<dim3(32, 16, 8), 256, 0, stream>>>(value, Vt);
    gemm128<512, 0><<<256, 256, 0, stream>>>(Xq, Wqbf, bq, nullptr, (void*)Qbf, 0.125f);
    gemm128<512, 0><<<256, 256, 0, stream>>>(Xk, Wkbf, bk, nullptr, (void*)Kbf, 1.0f);
    fused_attn<<<dim3(16, 64), 1024, 0, stream>>>(Qbf, Kbf, Vt, attn, AV);
    gemm128<4096, 1><<<256, 256, 0, stream>>>(AV, Wobf, bo, value, (void*)out, 0.f);
    ln_kernel<<<2048, 256, 0, stream>>>(out, gamma, beta);
}